// Round 22
// baseline (155.492 us; speedup 1.0000x reference)
//
#include <hip/hip_runtime.h>
#include <hip/hip_bf16.h>

typedef short s16x8 __attribute__((ext_vector_type(8)));
typedef float f32x4 __attribute__((ext_vector_type(4)));
typedef float f32x16 __attribute__((ext_vector_type(16)));
typedef unsigned short u16;
typedef unsigned int   u32;
typedef u16 u16x4 __attribute__((ext_vector_type(4)));

#define SEQ  1370
#define CH   1024
#define NH   16
#define HD   64
#define BN   5480      // 4*1370
#define MPAD 5504      // 43*128
#define NPAD 1408      // 44*32
#define NQT  43        // ceil(1370/32)
#define NKT64 22       // NPAD/64

// log2(e) folded into q scale: exp(x) = exp2(x*log2e)
#define QSCALE 0.18033688f   // 0.125 * 1.44269504089

__device__ __forceinline__ u16 f2bf(float f){
  union { float f; unsigned u; } v; v.f = f;
  unsigned u = v.u;
  return (u16)((u + 0x7FFFu + ((u >> 16) & 1u)) >> 16);   // RNE
}

__device__ __forceinline__ float bf2f(u16 b){
  union { unsigned u; float f; } v; v.u = ((u32)b) << 16;
  return v.f;
}

__device__ __forceinline__ u32 cvt_pk_bf16(float lo, float hi){
  u32 r;
  asm("v_cvt_pk_bf16_f32 %0, %1, %2" : "=v"(r) : "v"(lo), "v"(hi));
  return r;
}

#define GLOAD16(gp, lp) __builtin_amdgcn_global_load_lds( \
    (const __attribute__((address_space(1))) void*)(gp), \
    (__attribute__((address_space(3))) void*)(lp), 16, 0, 0)

// ---- fused cast: one launch for tokens+qkv_w+proj_w (G13 vectorized, 8/thread). ----
#define CAST_O0 (MPAD*CH)            // 5,636,096
#define CAST_O1 (CAST_O0 + 3*CH*CH)  // 8,781,824
#define CAST_TOT (CAST_O1 + CH*CH)   // 9,830,400

__global__ __launch_bounds__(256) void k_cast_all(
    const float* __restrict__ tokens, const float* __restrict__ qkv_w,
    const float* __restrict__ proj_w, u16* __restrict__ Xbf,
    u16* __restrict__ Wqkv, u16* __restrict__ Wproj)
{
  int i8 = (blockIdx.x * 256 + threadIdx.x) * 8;
  if(i8 >= CAST_TOT) return;
  const float* src; u16* dst; int off;
  if(i8 < CAST_O0){
    int row = i8 >> 10;
    s16x8 o = {0,0,0,0,0,0,0,0};
    if(row < BN){
      f32x4 a = *reinterpret_cast<const f32x4*>(tokens + i8);
      f32x4 b = *reinterpret_cast<const f32x4*>(tokens + i8 + 4);
#pragma unroll
      for(int j=0;j<4;j++){ o[j] = (short)f2bf(a[j]); o[4+j] = (short)f2bf(b[j]); }
    }
    *reinterpret_cast<s16x8*>(Xbf + i8) = o;
    return;
  } else if(i8 < CAST_O1){
    src = qkv_w; dst = Wqkv; off = i8 - CAST_O0;
  } else {
    src = proj_w; dst = Wproj; off = i8 - CAST_O1;
  }
  f32x4 a = *reinterpret_cast<const f32x4*>(src + off);
  f32x4 b = *reinterpret_cast<const f32x4*>(src + off + 4);
  s16x8 o;
#pragma unroll
  for(int j=0;j<4;j++){ o[j] = (short)f2bf(a[j]); o[4+j] = (short)f2bf(b[j]); }
  *reinterpret_cast<s16x8*>(dst + off) = o;
}

// ---- NT GEMM (r14 measured-best form, byte-exact) ----
template<int MODE, int NT>
__global__ __launch_bounds__(256,4) void k_gemm128(
    const u16* __restrict__ A, const u16* __restrict__ Bw, const float* __restrict__ bias,
    u16* __restrict__ q, u16* __restrict__ kk_, u16* __restrict__ vv, float* __restrict__ out)
{
  constexpr int NF = NT/32;
  __shared__ u16 As[128*64];     // [row][64], rows 128B; swizzled granule order
  __shared__ u16 Bs[NT*64];
  const int t = threadIdx.x;
  const int lane = t & 63;
  const int w = t >> 6;
  const int wm = w >> 1, wn = w & 1;
  const int g = lane >> 4, lr = lane & 15;

  const int bid = blockIdx.x;
  const int xcd = bid & 7, idx = bid >> 3;
  const int xr = xcd & 3, yr = xcd >> 2;
  constexpr int YLOC = (MODE == 0) ? 12 : 8;
  const int x = xr*11 + idx % 11;
  const int y = yr*YLOC + idx / 11;
  if(x >= MPAD/128) return;
  const int m0 = x*128, n0 = y*NT;

  const int swc = ((t & 7) ^ ((t >> 3) & 7)) * 8;
  const u16* ga0 = A  + (size_t)(m0 + (t >> 3)) * 1024 + swc;
  const u16* gb0 = Bw + (size_t)(n0 + (t >> 3)) * 1024 + swc;

  f32x4 z = {0.f,0.f,0.f,0.f};
  f32x4 acc[4][NF];
#pragma unroll
  for(int mf=0;mf<4;mf++)
#pragma unroll
    for(int nf=0;nf<NF;nf++) acc[mf][nf] = z;

  for(int k0 = 0; k0 < 1024; k0 += 64){
#pragma unroll
    for(int j=0;j<4;j++)
      GLOAD16(ga0 + k0 + j*32*1024, As + j*2048 + w*512);
#pragma unroll
    for(int j=0;j<NF;j++)
      GLOAD16(gb0 + k0 + j*32*1024, Bs + j*2048 + w*512);
    __syncthreads();
#pragma unroll
    for(int kk=0; kk<2; kk++){
      s16x8 af[4], bf[NF];
#pragma unroll
      for(int mf = 0; mf < 4; mf++)
        af[mf] = *reinterpret_cast<const s16x8*>(&As[(wm*64 + mf*16 + lr)*64 + ((kk*4+g) ^ (lr&7))*8]);
#pragma unroll
      for(int nf = 0; nf < NF; nf++)
        bf[nf] = *reinterpret_cast<const s16x8*>(&Bs[(wn*16*NF + nf*16 + lr)*64 + ((kk*4+g) ^ (lr&7))*8]);
#pragma unroll
      for(int mf = 0; mf < 4; mf++)
#pragma unroll
        for(int nf = 0; nf < NF; nf++)
          acc[mf][nf] = __builtin_amdgcn_mfma_f32_16x16x32_bf16(af[mf], bf[nf], acc[mf][nf], 0,0,0);
    }
    __syncthreads();
  }

#pragma unroll
  for(int mf = 0; mf < 4; mf++){
#pragma unroll
    for(int nf = 0; nf < NF; nf++){
      int colc = n0 + wn*16*NF + nf*16 + lr;
      float bb = bias[colc];
      if constexpr (MODE == 0){
        int tt = colc >> 10, h = (colc >> 6) & 15, cc = colc & 63;
        const int rowb = m0 + wm*64 + mf*16 + g*4;
        if(tt == 2){
          int b = rowb / SEQ;
          int nb = rowb - b*SEQ;
          if(rowb + 3 < BN && nb + 4 <= SEQ && (nb & 3) == 0){
            int bh = b*NH + h;
            int ktv = nb >> 6, kh = (nb >> 4) & 3, hiv = (nb >> 3) & 1;
            int e0 = nb & 7;
            int dtv = cc >> 5, colr = cc & 31;
            u16x4 ov;
#pragma unroll
            for(int r=0;r<4;r++) ov[r] = f2bf(acc[mf][nf][r] + bb);
            *reinterpret_cast<u16x4*>(vv +
              (size_t)((((bh*22 + ktv)*4 + kh)*2 + dtv)*2 + hiv)*256 + colr*8 + e0) = ov;
          } else {
#pragma unroll
            for(int r = 0; r < 4; r++){
              int row = rowb + r;
              if(row >= BN) continue;
              int b2 = row / SEQ, n = row - b2*SEQ;
              int bh = b2*NH + h;
              int ktv = n >> 6, kh = (n >> 4) & 3, hiv = (n >> 3) & 1, e = n & 7;
              int dtv = cc >> 5, colr = cc & 31;
              vv[(size_t)((((bh*22 + ktv)*4 + kh)*2 + dtv)*2 + hiv)*256 + colr*8 + e]
                = f2bf(acc[mf][nf][r] + bb);
            }
          }
        } else {
#pragma unroll
          for(int r = 0; r < 4; r++){
            int row = rowb + r;
            if(row >= BN) continue;
            int b = row / SEQ, n = row - b*SEQ;
            int bh = b*NH + h;
            int gg = n >> 5, colr = n & 31;
            int dtv = cc >> 4, hiq = (cc >> 3) & 1, e = cc & 7;
            size_t fidx = (size_t)(((bh*44 + gg)*4 + dtv)*2 + hiq)*256 + colr*8 + e;
            float v = acc[mf][nf][r] + bb;
            if(tt == 0) q  [fidx] = f2bf(v * QSCALE);
            else        kk_[fidx] = f2bf(v);
          }
        }
      } else {
#pragma unroll
        for(int r = 0; r < 4; r++){
          int row = m0 + wm*64 + mf*16 + g*4 + r;
          if(row >= BN) continue;
          out[(size_t)row * CH + colc] = acc[mf][nf][r] + bb;
        }
      }
    }
  }
}

// ---- flash attention split-K2: grid 1408 = 704 x 2 halves; each block does 11
// K-tiles, writes unnormalized numerator (bf16) + denominator (f32). Partials
// combine by PURE ADDITION (m==0 exact softmax, no max-rescale). (256,4): 4
// blocks/CU resident (was grid-capped at 2.75) — block-TLP, the one lever that
// worked this session. Np layout [bh][qt<43][row32][d64] bf16. ----
__global__ __launch_bounds__(256,4) void k_attn_sk2(
    const u16* __restrict__ Qf, const u16* __restrict__ Kf,
    const u16* __restrict__ Vf, u16* __restrict__ NpA, u16* __restrict__ NpB,
    float* __restrict__ LpA, float* __restrict__ LpB)
{
  __shared__ u16 Kl[2][4096];
  __shared__ u16 Vl[2][4096];
  const int bid2 = blockIdx.x;                // 0..1407
  const int half = bid2 & 1;
  const int bid = bid2 >> 1;                  // 0..703
  const int swz = (bid & 7)*88 + (bid >> 3);  // bijective: 704 = 8*88
  const int bh = swz / 11;
  const int qg = swz - bh*11;
  const int w = threadIdx.x >> 6;
  int qt = qg*4 + w;
  const bool wr = (qt < NQT);
  if(!wr) qt = NQT - 1;                       // dup wave: recompute, no store
  const int lane = threadIdx.x & 63;
  const int col = lane & 31;
  const int hi  = lane >> 5;
  const int n0  = qt * 32;
  const int lofs = hi*256 + col*8;

  s16x8 qf[4];
  {
    const u16* qfb = Qf + (size_t)(bh*44 + qt)*2048 + lofs;
#pragma unroll
    for(int dt=0; dt<4; dt++)
      qf[dt] = *reinterpret_cast<const s16x8*>(qfb + dt*512);
  }
  const u16* kfb = Kf + (size_t)bh*44*2048;
  const u16* vfb = Vf + (size_t)bh*22*4096;

#define STAGE_T(KT, CB) { \
  const u16* gk_ = kfb + (size_t)(KT)*4096 + w*1024 + lane*8; \
  const u16* gv_ = vfb + (size_t)(KT)*4096 + w*1024 + lane*8; \
  GLOAD16(gk_,       &Kl[CB][w*1024]); \
  GLOAD16(gk_ + 512, &Kl[CB][w*1024 + 512]); \
  GLOAD16(gv_,       &Vl[CB][w*1024]); \
  GLOAD16(gv_ + 512, &Vl[CB][w*1024 + 512]); }

  f32x16 accO[2];
  f32x16 accL;
#pragma unroll
  for(int i=0;i<16;i++){ accO[0][i]=0.f; accO[1][i]=0.f; accL[i]=0.f; }
  const s16x8 onesf = {(short)0x3F80,(short)0x3F80,(short)0x3F80,(short)0x3F80,
                       (short)0x3F80,(short)0x3F80,(short)0x3F80,(short)0x3F80};

  const int kt0 = half * 11, ktE = kt0 + 11;
  STAGE_T(kt0, kt0 & 1);
  asm volatile("s_waitcnt vmcnt(0)" ::: "memory");
  __builtin_amdgcn_s_barrier();

  for(int kt = kt0; kt < ktE; kt++){
    const int kj0 = kt * 64;
    const int cur = kt & 1;
    if(kt + 1 < ktE) STAGE_T(kt + 1, cur^1);
    // ---- QK^T (swapped), K frags from LDS ----
    f32x16 St[2];
#pragma unroll
    for(int s=0;s<2;s++){
#pragma unroll
      for(int i=0;i<16;i++) St[s][i]=0.f;
#pragma unroll
      for(int dt=0;dt<4;dt++){
        s16x8 kf = *reinterpret_cast<const s16x8*>(&Kl[cur][s*2048 + dt*512 + lofs]);
        St[s] = __builtin_amdgcn_mfma_f32_32x32x16_bf16(kf, qf[dt], St[s], 0,0,0);
      }
    }
    // ---- p = 2^S (exact softmax with m=0; masked tail -> 0) ----
    float p[32];
    if(kj0 + 64 <= SEQ){
#pragma unroll
      for(int i=0;i<32;i++) p[i] = exp2f(St[i>>4][i&15]);
    } else {
#pragma unroll
      for(int s=0;s<2;s++)
#pragma unroll
        for(int r=0;r<16;r++){
          int k = kj0 + s*32 + (r&3) + 8*(r>>2) + 4*hi;
          p[s*16+r] = (k < SEQ) ? exp2f(St[s][r]) : 0.f;
        }
    }
    // ---- P repack (T12) ----
    union PF { u32 w[4]; s16x8 v; } pf[4];
#pragma unroll
    for(int s=0;s<2;s++){
#pragma unroll
      for(int hh=0; hh<2; hh++){
        const int b0 = s*16 + hh*8;
        u32 w0 = cvt_pk_bf16(p[b0+0], p[b0+1]);
        u32 w1 = cvt_pk_bf16(p[b0+2], p[b0+3]);
        u32 w2 = cvt_pk_bf16(p[b0+4], p[b0+5]);
        u32 w3 = cvt_pk_bf16(p[b0+6], p[b0+7]);
        auto r02 = __builtin_amdgcn_permlane32_swap(w0, w2, false, false);
        auto r13 = __builtin_amdgcn_permlane32_swap(w1, w3, false, false);
        pf[s*2+hh].w[0] = r02[0];
        pf[s*2+hh].w[1] = r13[0];
        pf[s*2+hh].w[2] = r02[1];
        pf[s*2+hh].w[3] = r13[1];
      }
    }
    // ---- PV + denominator ----
#pragma unroll
    for(int kh=0; kh<4; kh++){
#pragma unroll
      for(int dt=0; dt<2; dt++){
        s16x8 vf = *reinterpret_cast<const s16x8*>(&Vl[cur][(kh*2+dt)*512 + lofs]);
        accO[dt] = __builtin_amdgcn_mfma_f32_32x32x16_bf16(vf, pf[kh].v, accO[dt], 0,0,0);
      }
      accL = __builtin_amdgcn_mfma_f32_32x32x16_bf16(onesf, pf[kh].v, accL, 0,0,0);
    }
    asm volatile("s_waitcnt vmcnt(0)" ::: "memory");
    __builtin_amdgcn_s_barrier();
  }

  // ---- epilogue: store UNNORMALIZED numerator + denominator partials ----
  if(wr){
    u16* np = (half ? NpB : NpA) + (size_t)(bh*43 + qt)*2048 + col*64;
    float* lp = (half ? LpB : LpA);
#pragma unroll
    for(int dt=0; dt<2; dt++)
#pragma unroll
      for(int qd=0; qd<4; qd++){
        u16x4 ov;
#pragma unroll
        for(int j=0;j<4;j++) ov[j] = f2bf(accO[dt][qd*4+j]);
        *reinterpret_cast<u16x4*>(np + dt*32 + qd*8 + hi*4) = ov;
      }
    lp[(bh*43 + qt)*32 + col] = accL[0];   // hi=0/1 write identical values (benign)
  }
}

// ---- merge: OM[b*SEQ+n][h*64+d] = (Na+Nb)/(la+lb); skips n>=SEQ rows ----
#define MERGE_TOT (64*43*2048)   // 5,636,096 elems; /8/256 = 2752 blocks exactly

__global__ __launch_bounds__(256) void k_merge(
    const u16* __restrict__ NpA, const u16* __restrict__ NpB,
    const float* __restrict__ LpA, const float* __restrict__ LpB,
    u16* __restrict__ OM)
{
  int idx8 = (blockIdx.x * 256 + threadIdx.x) * 8;
  if(idx8 >= MERGE_TOT) return;
  int bh  = idx8 / (43*2048);
  int rem = idx8 - bh*(43*2048);
  int qt  = rem >> 11;
  int rr  = rem & 2047;
  int row = rr >> 6, d0 = rr & 63;
  int n = qt*32 + row;
  if(n >= SEQ) return;
  int li = (bh*43 + qt)*32 + row;
  float inv = 1.0f / (LpA[li] + LpB[li]);
  s16x8 a = *reinterpret_cast<const s16x8*>(NpA + idx8);
  s16x8 b = *reinterpret_cast<const s16x8*>(NpB + idx8);
  s16x8 o;
#pragma unroll
  for(int j=0;j<8;j++)
    o[j] = (short)f2bf((bf2f((u16)a[j]) + bf2f((u16)b[j])) * inv);
  int bb = bh >> 4, h = bh & 15;
  *reinterpret_cast<s16x8*>(OM + ((size_t)(bb*SEQ + n))*CH + h*HD + d0) = o;
}

extern "C" void kernel_launch(void* const* d_in, const int* in_sizes, int n_in,
                              void* d_out, int out_size, void* d_ws, size_t ws_size,
                              hipStream_t stream)
{
  const float* tokens = (const float*)d_in[0];
  const float* qkv_w  = (const float*)d_in[1];
  const float* qkv_b  = (const float*)d_in[2];
  const float* proj_w = (const float*)d_in[3];
  const float* proj_b = (const float*)d_in[4];
  float* out = (float*)d_out;

  char* ws = (char*)d_ws;
  u16* Xbf   = (u16*)(ws);              // MPAD*1024*2        = 11,272,192 B
  u16* Wqkv  = (u16*)(ws + 11272192);   // 3072*1024*2        =  6,291,456
  u16* Wproj = (u16*)(ws + 17563648);   // 1024*1024*2        =  2,097,152
  u16* Qfb   = (u16*)(ws + 19660800);   // 64*44*2048*2       = 11,534,336
  u16* Kfb   = (u16*)(ws + 31195136);
  u16* Vfb   = (u16*)(ws + 42729472);
  u16* AttO  = (u16*)(ws + 65798144);   // 11,272,192; end 77,070,336
  // Aliased (lifetime-disjoint) split-K buffers — NO new ws usage:
  u16*   NpA = (u16*)(ws);              // reuses Xbf region: 64*43*2048*2 = 11,272,192 (exact)
  float* LpA = (float*)(ws + 11272192); // in dead Wqkv region: 64*43*32*4 = 352,256
  float* LpB = (float*)(ws + 11624448); // + 352,256 (ends 11,976,704 < 17,563,648)
  u16*   NpB = AttO;                    // reuses AttO region (exact size match)
  u16*   OM  = Qfb;                     // merged output reuses Qfb region (dead after attn)

  k_cast_all<<<dim3(CAST_TOT/2048), 256, 0, stream>>>(tokens, qkv_w, proj_w, Xbf, Wqkv, Wproj);

  k_gemm128<0,128><<<dim3(1056), 256, 0, stream>>>(Xbf, Wqkv, qkv_b, Qfb, Kfb, Vfb, nullptr);
  k_attn_sk2<<<dim3(1408), 256, 0, stream>>>(Qfb, Kfb, Vfb, NpA, NpB, LpA, LpB);
  k_merge<<<dim3(MERGE_TOT/2048), 256, 0, stream>>>(NpA, NpB, LpA, LpB, OM);
  k_gemm128<1,64><<<dim3(704), 256, 0, stream>>>(OM, Wproj, proj_b, nullptr, nullptr, nullptr, out);
}

// Round 23
// 150.244 us; speedup vs baseline: 1.0349x; 1.0349x over previous
//
#include <hip/hip_runtime.h>
#include <hip/hip_bf16.h>

typedef short s16x8 __attribute__((ext_vector_type(8)));
typedef float f32x4 __attribute__((ext_vector_type(4)));
typedef float f32x16 __attribute__((ext_vector_type(16)));
typedef unsigned short u16;
typedef unsigned int   u32;
typedef u16 u16x4 __attribute__((ext_vector_type(4)));

#define SEQ  1370
#define CH   1024
#define NH   16
#define HD   64
#define BN   5480      // 4*1370
#define MPAD 5504      // 43*128
#define NPAD 1408      // 44*32
#define NQT  43        // ceil(1370/32)
#define NKT64 22       // NPAD/64

// log2(e) folded into q scale: exp(x) = exp2(x*log2e)
#define QSCALE 0.18033688f   // 0.125 * 1.44269504089

// Fragment-linear layouts (attn loads/stages are base + lane*16B, fully coalesced):
//  Qf/Kf[bh][gg][dt][hi][col][8]  : gg=n>>5 (44), dt=cc>>4 (4), hi=(cc>>3)&1, col=n&31, e=cc&7
//  Vf[bh][kt][kh][dtv][hi][col][8]: kt=n>>6 (22), kh=(n>>4)&3, hi=(n>>3)&1, e=n&7, dtv=cc>>5, col=cc&31
//  K tile kt occupies u16 [kt*4096, kt*4096+4096) of Kf[bh] (8KB contiguous); V same.

__device__ __forceinline__ u16 f2bf(float f){
  union { float f; unsigned u; } v; v.f = f;
  unsigned u = v.u;
  return (u16)((u + 0x7FFFu + ((u >> 16) & 1u)) >> 16);   // RNE
}

__device__ __forceinline__ u32 cvt_pk_bf16(float lo, float hi){
  u32 r;
  asm("v_cvt_pk_bf16_f32 %0, %1, %2" : "=v"(r) : "v"(lo), "v"(hi));
  return r;
}

#define GLOAD16(gp, lp) __builtin_amdgcn_global_load_lds( \
    (const __attribute__((address_space(1))) void*)(gp), \
    (__attribute__((address_space(3))) void*)(lp), 16, 0, 0)

// ---- fused cast: one launch for tokens+qkv_w+proj_w (G13 vectorized, 8/thread). ----
#define CAST_O0 (MPAD*CH)            // 5,636,096
#define CAST_O1 (CAST_O0 + 3*CH*CH)  // 8,781,824
#define CAST_TOT (CAST_O1 + CH*CH)   // 9,830,400

__global__ __launch_bounds__(256) void k_cast_all(
    const float* __restrict__ tokens, const float* __restrict__ qkv_w,
    const float* __restrict__ proj_w, u16* __restrict__ Xbf,
    u16* __restrict__ Wqkv, u16* __restrict__ Wproj)
{
  int i8 = (blockIdx.x * 256 + threadIdx.x) * 8;
  if(i8 >= CAST_TOT) return;
  const float* src; u16* dst; int off;
  if(i8 < CAST_O0){
    // tokens with M-pad: rows >= BN zero-filled (1024%8==0 -> row uniform per 8-group)
    int row = i8 >> 10;
    s16x8 o = {0,0,0,0,0,0,0,0};
    if(row < BN){
      f32x4 a = *reinterpret_cast<const f32x4*>(tokens + i8);
      f32x4 b = *reinterpret_cast<const f32x4*>(tokens + i8 + 4);
#pragma unroll
      for(int j=0;j<4;j++){ o[j] = (short)f2bf(a[j]); o[4+j] = (short)f2bf(b[j]); }
    }
    *reinterpret_cast<s16x8*>(Xbf + i8) = o;
    return;
  } else if(i8 < CAST_O1){
    src = qkv_w; dst = Wqkv; off = i8 - CAST_O0;
  } else {
    src = proj_w; dst = Wproj; off = i8 - CAST_O1;
  }
  f32x4 a = *reinterpret_cast<const f32x4*>(src + off);
  f32x4 b = *reinterpret_cast<const f32x4*>(src + off + 4);
  s16x8 o;
#pragma unroll
  for(int j=0;j<4;j++){ o[j] = (short)f2bf(a[j]); o[4+j] = (short)f2bf(b[j]); }
  *reinterpret_cast<s16x8*>(dst + off) = o;
}

// ---- NT GEMM (r14 measured-best form, byte-exact): 128xNT tile, BK=64,
// single-buffer global_load_lds, XOR-swizzled LDS, (256,4) drain-overlap TLP.
// At the m102 shape curve for this problem size — structure's expected perf. ----
template<int MODE, int NT>
__global__ __launch_bounds__(256,4) void k_gemm128(
    const u16* __restrict__ A, const u16* __restrict__ Bw, const float* __restrict__ bias,
    u16* __restrict__ q, u16* __restrict__ kk_, u16* __restrict__ vv, float* __restrict__ out)
{
  constexpr int NF = NT/32;
  __shared__ u16 As[128*64];     // [row][64], rows 128B; swizzled granule order
  __shared__ u16 Bs[NT*64];
  const int t = threadIdx.x;
  const int lane = t & 63;
  const int w = t >> 6;
  const int wm = w >> 1, wn = w & 1;
  const int g = lane >> 4, lr = lane & 15;

  const int bid = blockIdx.x;
  const int xcd = bid & 7, idx = bid >> 3;
  const int xr = xcd & 3, yr = xcd >> 2;
  constexpr int YLOC = (MODE == 0) ? 12 : 8;
  const int x = xr*11 + idx % 11;
  const int y = yr*YLOC + idx / 11;
  if(x >= MPAD/128) return;
  const int m0 = x*128, n0 = y*NT;

  // inverse-swizzled global source: thread t stages global 16B-chunk (t&7)^((t>>3)&7)
  // of row (t>>3)+j*32 into LDS granule t&7 of that row (linear dest).
  const int swc = ((t & 7) ^ ((t >> 3) & 7)) * 8;
  const u16* ga0 = A  + (size_t)(m0 + (t >> 3)) * 1024 + swc;
  const u16* gb0 = Bw + (size_t)(n0 + (t >> 3)) * 1024 + swc;

  f32x4 z = {0.f,0.f,0.f,0.f};
  f32x4 acc[4][NF];
#pragma unroll
  for(int mf=0;mf<4;mf++)
#pragma unroll
    for(int nf=0;nf<NF;nf++) acc[mf][nf] = z;

  for(int k0 = 0; k0 < 1024; k0 += 64){
#pragma unroll
    for(int j=0;j<4;j++)
      GLOAD16(ga0 + k0 + j*32*1024, As + j*2048 + w*512);
#pragma unroll
    for(int j=0;j<NF;j++)
      GLOAD16(gb0 + k0 + j*32*1024, Bs + j*2048 + w*512);
    __syncthreads();              // vmcnt(0) drain + barrier: tiles resident
#pragma unroll
    for(int kk=0; kk<2; kk++){
      s16x8 af[4], bf[NF];
#pragma unroll
      for(int mf = 0; mf < 4; mf++)
        af[mf] = *reinterpret_cast<const s16x8*>(&As[(wm*64 + mf*16 + lr)*64 + ((kk*4+g) ^ (lr&7))*8]);
#pragma unroll
      for(int nf = 0; nf < NF; nf++)
        bf[nf] = *reinterpret_cast<const s16x8*>(&Bs[(wn*16*NF + nf*16 + lr)*64 + ((kk*4+g) ^ (lr&7))*8]);
#pragma unroll
      for(int mf = 0; mf < 4; mf++)
#pragma unroll
        for(int nf = 0; nf < NF; nf++)
          acc[mf][nf] = __builtin_amdgcn_mfma_f32_16x16x32_bf16(af[mf], bf[nf], acc[mf][nf], 0,0,0);
    }
    __syncthreads();              // all reads done before next overwrite
  }

#pragma unroll
  for(int mf = 0; mf < 4; mf++){
#pragma unroll
    for(int nf = 0; nf < NF; nf++){
      int colc = n0 + wn*16*NF + nf*16 + lr;
      float bb = bias[colc];
      if constexpr (MODE == 0){
        // blocks never straddle the q/k/v 1024-col boundaries (128 | 1024)
        int tt = colc >> 10, h = (colc >> 6) & 15, cc = colc & 63;
        const int rowb = m0 + wm*64 + mf*16 + g*4;   // row of r=0
        if(tt == 2){
          int b = rowb / SEQ;
          int nb = rowb - b*SEQ;
          // vector path: all 4 rows in-bounds, same b, nb 4-aligned
          // (SEQ%4==2 -> b=1,3 have nb≡2 mod 4: e-octet crossing -> scalar path)
          if(rowb + 3 < BN && nb + 4 <= SEQ && (nb & 3) == 0){
            int bh = b*NH + h;
            int ktv = nb >> 6, kh = (nb >> 4) & 3, hiv = (nb >> 3) & 1;
            int e0 = nb & 7;         // 0 or 4; e0+3 <= 7, kh/hiv constant
            int dtv = cc >> 5, colr = cc & 31;
            u16x4 ov;
#pragma unroll
            for(int r=0;r<4;r++) ov[r] = f2bf(acc[mf][nf][r] + bb);
            *reinterpret_cast<u16x4*>(vv +
              (size_t)((((bh*22 + ktv)*4 + kh)*2 + dtv)*2 + hiv)*256 + colr*8 + e0) = ov;
          } else {
#pragma unroll
            for(int r = 0; r < 4; r++){
              int row = rowb + r;
              if(row >= BN) continue;
              int b2 = row / SEQ, n = row - b2*SEQ;
              int bh = b2*NH + h;
              int ktv = n >> 6, kh = (n >> 4) & 3, hiv = (n >> 3) & 1, e = n & 7;
              int dtv = cc >> 5, colr = cc & 31;
              vv[(size_t)((((bh*22 + ktv)*4 + kh)*2 + dtv)*2 + hiv)*256 + colr*8 + e]
                = f2bf(acc[mf][nf][r] + bb);
            }
          }
        } else {
#pragma unroll
          for(int r = 0; r < 4; r++){
            int row = rowb + r;
            if(row >= BN) continue;
            int b = row / SEQ, n = row - b*SEQ;
            int bh = b*NH + h;
            int gg = n >> 5, colr = n & 31;
            int dtv = cc >> 4, hiq = (cc >> 3) & 1, e = cc & 7;
            size_t fidx = (size_t)(((bh*44 + gg)*4 + dtv)*2 + hiq)*256 + colr*8 + e;
            float v = acc[mf][nf][r] + bb;
            if(tt == 0) q  [fidx] = f2bf(v * QSCALE);
            else        kk_[fidx] = f2bf(v);
          }
        }
      } else {
#pragma unroll
        for(int r = 0; r < 4; r++){
          int row = m0 + wm*64 + mf*16 + g*4 + r;   // C/D: col=lane&15, row=(lane>>4)*4+reg
          if(row >= BN) continue;
          out[(size_t)row * CH + colc] = acc[mf][nf][r] + bb;
        }
      }
    }
  }
}

// ---- flash attention v9b (measured best, r21): LDS-staged K/V double-buffered,
// no-max exact softmax (m==0), denominator on the MFMA pipe, exp2, no setprio.
// r3/r11/r18/r22 lessons: in-wave pipelining spills; split-K merge cost exceeds
// its occupancy gain; this structure is the explored-space optimum. ----
__global__ __launch_bounds__(256,3) void k_attn9(
    const u16* __restrict__ Qf, const u16* __restrict__ Kf,
    const u16* __restrict__ Vf, u16* __restrict__ O)
{
  __shared__ u16 Kl[2][4096];   // 8KB per buffer: K tile (2 s-frags x 4 dt x 1KB)
  __shared__ u16 Vl[2][4096];   // 8KB per buffer: V tile (8 frags x 1KB)
  const int bid = blockIdx.x;                 // 0..703
  const int swz = (bid & 7)*88 + (bid >> 3);  // bijective: 704 = 8*88
  const int bh = swz / 11;                    // 8 bh per XCD -> K/V in its L2
  const int qg = swz - bh*11;
  const int w = threadIdx.x >> 6;
  int qt = qg*4 + w;
  const bool wr = (qt < NQT);
  if(!wr) qt = NQT - 1;                       // dup wave: recompute, no store
  const int lane = threadIdx.x & 63;
  const int col = lane & 31;
  const int hi  = lane >> 5;
  const int n0  = qt * 32;
  const int lofs = hi*256 + col*8;            // per-lane 16B slot within a 1KB fragment

  s16x8 qf[4];
  {
    const u16* qfb = Qf + (size_t)(bh*44 + qt)*2048 + lofs;
#pragma unroll
    for(int dt=0; dt<4; dt++)
      qf[dt] = *reinterpret_cast<const s16x8*>(qfb + dt*512);
  }
  const u16* kfb = Kf + (size_t)bh*44*2048;   // K tile kt at + kt*4096 (u16)
  const u16* vfb = Vf + (size_t)bh*22*4096;   // V tile kt at + kt*4096 (u16)

#define STAGE_T(KT, CB) { \
  const u16* gk_ = kfb + (size_t)(KT)*4096 + w*1024 + lane*8; \
  const u16* gv_ = vfb + (size_t)(KT)*4096 + w*1024 + lane*8; \
  GLOAD16(gk_,       &Kl[CB][w*1024]); \
  GLOAD16(gk_ + 512, &Kl[CB][w*1024 + 512]); \
  GLOAD16(gv_,       &Vl[CB][w*1024]); \
  GLOAD16(gv_ + 512, &Vl[CB][w*1024 + 512]); }

  f32x16 accO[2];
  f32x16 accL;                  // ones-row PV: accL[0] = softmax denominator
#pragma unroll
  for(int i=0;i<16;i++){ accO[0][i]=0.f; accO[1][i]=0.f; accL[i]=0.f; }
  const s16x8 onesf = {(short)0x3F80,(short)0x3F80,(short)0x3F80,(short)0x3F80,
                       (short)0x3F80,(short)0x3F80,(short)0x3F80,(short)0x3F80};

  STAGE_T(0, 0);
  asm volatile("s_waitcnt vmcnt(0)" ::: "memory");
  __builtin_amdgcn_s_barrier();

  for(int kt = 0; kt < NKT64; kt++){
    const int kj0 = kt * 64;
    const int cur = kt & 1;
    if(kt + 1 < NKT64) STAGE_T(kt + 1, cur^1);   // prefetch next tile under compute
    // ---- QK^T (swapped), K frags from LDS ----
    f32x16 St[2];
#pragma unroll
    for(int s=0;s<2;s++){
#pragma unroll
      for(int i=0;i<16;i++) St[s][i]=0.f;
#pragma unroll
      for(int dt=0;dt<4;dt++){
        s16x8 kf = *reinterpret_cast<const s16x8*>(&Kl[cur][s*2048 + dt*512 + lofs]);
        St[s] = __builtin_amdgcn_mfma_f32_32x32x16_bf16(kf, qf[dt], St[s], 0,0,0);
      }
    }
    // ---- p = 2^S (exact softmax with m=0; masked tail -> 0) ----
    float p[32];
    if(kj0 + 64 <= SEQ){
#pragma unroll
      for(int i=0;i<32;i++) p[i] = exp2f(St[i>>4][i&15]);
    } else {
#pragma unroll
      for(int s=0;s<2;s++)
#pragma unroll
        for(int r=0;r<16;r++){
          int k = kj0 + s*32 + (r&3) + 8*(r>>2) + 4*hi;
          p[s*16+r] = (k < SEQ) ? exp2f(St[s][r]) : 0.f;
        }
    }
    // ---- P repack (T12) ----
    union PF { u32 w[4]; s16x8 v; } pf[4];
#pragma unroll
    for(int s=0;s<2;s++){
#pragma unroll
      for(int hh=0; hh<2; hh++){
        const int b0 = s*16 + hh*8;
        u32 w0 = cvt_pk_bf16(p[b0+0], p[b0+1]);
        u32 w1 = cvt_pk_bf16(p[b0+2], p[b0+3]);
        u32 w2 = cvt_pk_bf16(p[b0+4], p[b0+5]);
        u32 w3 = cvt_pk_bf16(p[b0+6], p[b0+7]);
        auto r02 = __builtin_amdgcn_permlane32_swap(w0, w2, false, false);
        auto r13 = __builtin_amdgcn_permlane32_swap(w1, w3, false, false);
        pf[s*2+hh].w[0] = r02[0];
        pf[s*2+hh].w[1] = r13[0];
        pf[s*2+hh].w[2] = r02[1];
        pf[s*2+hh].w[3] = r13[1];
      }
    }
    // ---- PV + denominator, V frags from LDS; sum rides the MFMA pipe ----
#pragma unroll
    for(int kh=0; kh<4; kh++){
#pragma unroll
      for(int dt=0; dt<2; dt++){
        s16x8 vf = *reinterpret_cast<const s16x8*>(&Vl[cur][(kh*2+dt)*512 + lofs]);
        accO[dt] = __builtin_amdgcn_mfma_f32_32x32x16_bf16(vf, pf[kh].v, accO[dt], 0,0,0);
      }
      accL = __builtin_amdgcn_mfma_f32_32x32x16_bf16(onesf, pf[kh].v, accL, 0,0,0);
    }
    // ---- tile boundary: prefetch landed (vmcnt 0), reads consumed by MFMA ----
    asm volatile("s_waitcnt vmcnt(0)" ::: "memory");
    __builtin_amdgcn_s_barrier();
  }

  // ---- epilogue ----
  const int n = n0 + col;
  if(wr && n < SEQ){
    float inv = 1.0f / accL[0];
    const int b = bh >> 4, h = bh & 15;
    u16* orow = O + ((size_t)(b*SEQ + n))*CH + h*HD;
#pragma unroll
    for(int dt=0; dt<2; dt++)
#pragma unroll
      for(int qd=0; qd<4; qd++){
        u16x4 ov;
#pragma unroll
        for(int j=0;j<4;j++) ov[j] = f2bf(accO[dt][qd*4+j]*inv);
        *reinterpret_cast<u16x4*>(orow + dt*32 + qd*8 + hi*4) = ov;
      }
  }
}

extern "C" void kernel_launch(void* const* d_in, const int* in_sizes, int n_in,
                              void* d_out, int out_size, void* d_ws, size_t ws_size,
                              hipStream_t stream)
{
  const float* tokens = (const float*)d_in[0];
  const float* qkv_w  = (const float*)d_in[1];
  const float* qkv_b  = (const float*)d_in[2];
  const float* proj_w = (const float*)d_in[3];
  const float* proj_b = (const float*)d_in[4];
  float* out = (float*)d_out;

  char* ws = (char*)d_ws;
  u16* Xbf   = (u16*)(ws);              // MPAD*1024*2        = 11,272,192 B
  u16* Wqkv  = (u16*)(ws + 11272192);   // 3072*1024*2        =  6,291,456
  u16* Wproj = (u16*)(ws + 17563648);   // 1024*1024*2        =  2,097,152
  u16* Qfb   = (u16*)(ws + 19660800);   // 64*44*2048*2       = 11,534,336
  u16* Kfb   = (u16*)(ws + 31195136);
  u16* Vfb   = (u16*)(ws + 42729472);
  u16* AttO  = (u16*)(ws + 65798144);   // MPAD*1024*2

  k_cast_all<<<dim3(CAST_TOT/2048), 256, 0, stream>>>(tokens, qkv_w, proj_w, Xbf, Wqkv, Wproj);

  k_gemm128<0,128><<<dim3(1056), 256, 0, stream>>>(Xbf, Wqkv, qkv_b, Qfb, Kfb, Vfb, nullptr);
  k_attn9<<<dim3(704), 256, 0, stream>>>(Qfb, Kfb, Vfb, AttO);
  k_gemm128<1,64><<<dim3(704), 256, 0, stream>>>(AttO, Wproj, proj_b, nullptr, nullptr, nullptr, out);
}